// Round 7
// baseline (670.444 us; speedup 1.0000x reference)
//
#include <hip/hip_runtime.h>

// ---------------------------------------------------------------------------
// SelfAttentionLayer (talking-heads) on MI355X gfx950. Round 7.
// Attention v7 = v6 single-pass + 2-way j-split (512 blocks = 2 blocks/CU so
// barrier drains of one block overlap compute of the other). Blocks emit
// partial unnormalized U (f16) + partial l; attn_red sums, normalizes,
// applies mix2 + bsum, writes ob.
// GEMMs: out-proj/fc2 reverted to BN=128 (BN=64 was a round-4 regression).
// transpose_v fused with V column-sum (atomicAdd into bsum).
// ---------------------------------------------------------------------------

typedef _Float16 f16x8 __attribute__((ext_vector_type(8)));
typedef _Float16 f16x4 __attribute__((ext_vector_type(4)));
typedef float f32x4 __attribute__((ext_vector_type(4)));

#define B_ 4
#define N_ 1024
#define D_ 1024
#define H_ 16
#define DH_ 64
#define FF_ 4096
#define M_ (B_ * N_)

__device__ __forceinline__ float gelu_act(float x) {
  float z = 0.7978845608028654f * (x + 0.044715f * x * x * x);
  return x / (1.0f + __expf(-2.0f * z));
}

__device__ __forceinline__ void ld_lds16(const _Float16* g, _Float16* l) {
  __builtin_amdgcn_global_load_lds((const __attribute__((address_space(1))) void*)g,
                                   (__attribute__((address_space(3))) void*)l, 16, 0, 0);
}

__device__ __forceinline__ int swz8(int i) {
  return (((i >> 2) << 1) ^ (i & 3)) & 7;
}
// S/P plane addressing (v4..v6-proven): plane p stride 1032 f16, row i (64
// f16), col j chunk-swizzled; all access patterns <=2-way conflicts.
__device__ __forceinline__ int lds_off(int p, int i, int j) {
  int ch = ((j >> 3) ^ swz8(i) ^ ((p >> 2) << 1)) & 7;
  return p * 1032 + i * 64 + (ch << 3) + (j & 7);
}

// ---------------- fp32 -> fp16 cast (weights) ----------------
__global__ __launch_bounds__(256) void cast_f32_f16(const float* __restrict__ in,
                                                    _Float16* __restrict__ out, int n) {
  int i = (blockIdx.x * 256 + threadIdx.x) * 4;
  if (i >= n) return;
  float4 v = *(const float4*)(in + i);
  f16x4 o;
  o[0] = (_Float16)v.x; o[1] = (_Float16)v.y; o[2] = (_Float16)v.z; o[3] = (_Float16)v.w;
  *(f16x4*)(out + i) = o;
}

// ---------------- prep mix weights + zero bsum ----------------
__global__ __launch_bounds__(256) void prep_w(const float* __restrict__ W1,
                                              const float* __restrict__ W2,
                                              _Float16* __restrict__ w1f,
                                              _Float16* __restrict__ w2f,
                                              float* __restrict__ bsum) {
  int t = threadIdx.x;
  w1f[t] = (_Float16)W1[t];
  w2f[t] = (_Float16)W2[t];
  #pragma unroll
  for (int k = 0; k < 16; k++) bsum[t * 16 + k] = 0.f;
}

// ---------------- LayerNorm (row of 1024) -> fp16 ----------------
__global__ __launch_bounds__(256) void ln_f16(const float* __restrict__ x,
                                              const float* __restrict__ w,
                                              const float* __restrict__ b,
                                              _Float16* __restrict__ out) {
  int row = blockIdx.x;
  int tid = threadIdx.x;
  const float* xr = x + (size_t)row * D_;
  float4 v = *(const float4*)(xr + tid * 4);
  float s = v.x + v.y + v.z + v.w;
  float sq = v.x * v.x + v.y * v.y + v.z * v.z + v.w * v.w;
  #pragma unroll
  for (int off = 32; off > 0; off >>= 1) {
    s += __shfl_down(s, off);
    sq += __shfl_down(sq, off);
  }
  __shared__ float red[8];
  int wave = tid >> 6, lane = tid & 63;
  if (lane == 0) { red[wave] = s; red[4 + wave] = sq; }
  __syncthreads();
  float ts = red[0] + red[1] + red[2] + red[3];
  float tq = red[4] + red[5] + red[6] + red[7];
  float mean = ts * (1.0f / (float)D_);
  float var = tq * (1.0f / (float)D_) - mean * mean;
  float rs = rsqrtf(var + 1e-5f);
  float4 wv = *(const float4*)(w + tid * 4);
  float4 bv = *(const float4*)(b + tid * 4);
  f16x4 o;
  o[0] = (_Float16)((v.x - mean) * rs * wv.x + bv.x);
  o[1] = (_Float16)((v.y - mean) * rs * wv.y + bv.y);
  o[2] = (_Float16)((v.z - mean) * rs * wv.z + bv.z);
  o[3] = (_Float16)((v.w - mean) * rs * wv.w + bv.w);
  *(f16x4*)(out + (size_t)row * D_ + tid * 4) = o;
}

// ---------------- NT GEMM: C[M,N] = A[M,K] @ W[N,K]^T + bias ----------------
// 128x128 tile, BK=64, 256 thr (2x2 waves), global_load_lds width=16.
template <int EPI>
__global__ __launch_bounds__(256, 3) void gemm_nt(
    const _Float16* __restrict__ A, const _Float16* __restrict__ W,
    const float* __restrict__ bias, int M, int N, int K,
    _Float16* __restrict__ outB, float* __restrict__ outF,
    const float* __restrict__ res, const float* __restrict__ gamma) {
  __shared__ _Float16 As[128 * 64];
  __shared__ _Float16 Bs[128 * 64];
  int tid = threadIdx.x;
  int wave = tid >> 6, lane = tid & 63;
  int quad = lane >> 4, l16 = lane & 15;
  int wm = wave >> 1, wn = wave & 1;
  int m0 = blockIdx.y * 128, n0 = blockIdx.x * 128;
  int lrow = lane >> 3, lcol = (lane & 7) * 8;

  f32x4 zero = {0.f, 0.f, 0.f, 0.f};
  f32x4 acc[4][4];
  #pragma unroll
  for (int i = 0; i < 4; i++)
    #pragma unroll
    for (int j = 0; j < 4; j++) acc[i][j] = zero;

  for (int k0 = 0; k0 < K; k0 += 64) {
    __syncthreads();
    #pragma unroll
    for (int c = 0; c < 4; c++) {
      int rb = c * 32 + wave * 8;
      ld_lds16(A + (size_t)(m0 + rb + lrow) * K + k0 + lcol, As + rb * 64);
      ld_lds16(W + (size_t)(n0 + rb + lrow) * K + k0 + lcol, Bs + rb * 64);
    }
    __syncthreads();
    #pragma unroll
    for (int ks = 0; ks < 2; ks++) {
      int kk = ks * 32 + quad * 8;
      f16x8 a[4], bfr[4];
      #pragma unroll
      for (int i = 0; i < 4; i++) a[i] = *(const f16x8*)(As + (wm * 64 + i * 16 + l16) * 64 + kk);
      #pragma unroll
      for (int i = 0; i < 4; i++) bfr[i] = *(const f16x8*)(Bs + (wn * 64 + i * 16 + l16) * 64 + kk);
      #pragma unroll
      for (int mi = 0; mi < 4; mi++)
        #pragma unroll
        for (int ni = 0; ni < 4; ni++)
          acc[mi][ni] = __builtin_amdgcn_mfma_f32_16x16x32_f16(a[mi], bfr[ni], acc[mi][ni], 0, 0, 0);
    }
  }

  #pragma unroll
  for (int mi = 0; mi < 4; mi++) {
    int grow_base = m0 + wm * 64 + mi * 16 + quad * 4;
    #pragma unroll
    for (int ni = 0; ni < 4; ni++) {
      int gcol = n0 + wn * 64 + ni * 16 + l16;
      float bb = bias[gcol];
      float gm = (EPI == 1) ? gamma[gcol] : 0.f;
      #pragma unroll
      for (int r = 0; r < 4; r++) {
        size_t oi = (size_t)(grow_base + r) * N + gcol;
        float c = acc[mi][ni][r] + bb;
        if (EPI == 0) {
          outB[oi] = (_Float16)c;
        } else if (EPI == 1) {
          outF[oi] = res[oi] + gm * c;
        } else {
          outB[oi] = (_Float16)gelu_act(c);
        }
      }
    }
  }
}

// ---------------- V transpose + fused column sum ----------------
// vt[b][h][d][j] = V; bsum[b][h*64+d] += b2[h] * sum_j V[j][d] (atomic).
__global__ __launch_bounds__(256) void transpose_vsum(const _Float16* __restrict__ qkv,
                                                      const float* __restrict__ b2,
                                                      _Float16* __restrict__ vt,
                                                      float* __restrict__ bsum) {
  int jt = blockIdx.x;
  int h = blockIdx.y;
  int b = blockIdx.z;
  __shared__ _Float16 tl[64][68];
  int tid = threadIdx.x;
  int j0 = jt * 64;
  #pragma unroll
  for (int k = 0; k < 16; k++) {
    int idx = k * 256 + tid;
    int jr = idx >> 6, dc = idx & 63;
    tl[jr][dc] = qkv[(size_t)(b * N_ + j0 + jr) * (3 * D_) + 2 * D_ + h * 64 + dc];
  }
  __syncthreads();
  #pragma unroll
  for (int k = 0; k < 16; k++) {
    int idx = k * 256 + tid;
    int dr = idx >> 6, jc = idx & 63;
    vt[(size_t)((b * H_ + h) * DH_ + dr) * N_ + j0 + jc] = tl[jc][dr];
  }
  // fused partial V column-sum
  int d = tid & 63, ch = tid >> 6;
  float s = 0.f;
  #pragma unroll
  for (int k = 0; k < 16; k++) s += (float)tl[ch * 16 + k][d];
  atomicAdd(bsum + b * D_ + h * 64 + d, b2[h] * s);
}

// ---------------- Talking-heads attention v7: single pass, j-split ----------------
// grid (64 i-tiles, 2 j-halves, 4 b) = 512 blocks (2/CU), 1024 thr = 16 waves.
// Wave role: computeS h=wave; mix1 i=wave; PV e=wave.
// Emits partial unnormalized U (f16 [e][i][d]) and partial l per block.
__global__ __launch_bounds__(1024, 8) void attn_th(
    const _Float16* __restrict__ qkv, const _Float16* __restrict__ vt,
    const _Float16* __restrict__ w1f, const float* __restrict__ b1f,
    _Float16* __restrict__ upart, float* __restrict__ lpart) {
  __shared__ __align__(16) _Float16 SP[2 * 16512];  // S planes | P planes
  _Float16* Sp = SP;
  _Float16* Pp = SP + 16512;

  const int tid = threadIdx.x;
  const int wave = tid >> 6;
  const int lane = tid & 63;
  const int quad = lane >> 4, l16 = lane & 15;
  const int it = blockIdx.x;
  const int jh = blockIdx.y;
  const int b = blockIdx.z;
  const int i0 = it * 16;
  const size_t bN = (size_t)b * N_;
  const f32x4 zero = {0.f, 0.f, 0.f, 0.f};

  // Q fragments (head=wave), pre-scaled by DH^-1/2 = 0.125 (exact in f16)
  f16x8 qf[2];
  #pragma unroll
  for (int ks = 0; ks < 2; ks++) {
    f16x8 q = *(const f16x8*)(qkv + (bN + i0 + l16) * 3072 + wave * 64 + ks * 32 + quad * 8);
    #pragma unroll
    for (int e = 0; e < 8; e++) q[e] = q[e] * (_Float16)0.125f;
    qf[ks] = q;
  }
  // W1 B-fragment: B[k=h][n=e] = W1[e][h]
  f16x4 w1a = *(const f16x4*)(w1f + l16 * 16 + quad * 4);
  float b1v = b1f[l16];
  f32x4 b1i = {b1v, b1v, b1v, b1v};

  const _Float16* vbase = vt + (size_t)((b * H_ + wave) * DH_ + l16) * N_ + quad * 8;

  f32x4 uacc[4];
  #pragma unroll
  for (int nt = 0; nt < 4; nt++) uacc[nt] = zero;
  float lacc = 0.f;

  // K fragments for current tile (reloaded in place; prefetched cross-barrier)
  f16x8 kcur[4][2];
  auto loadK = [&](int j0) {
    #pragma unroll
    for (int jb = 0; jb < 4; jb++) {
      const _Float16* kb = qkv + (bN + j0 + jb * 16 + l16) * 3072 + 1024 + wave * 64 + quad * 8;
      kcur[jb][0] = *(const f16x8*)kb;
      kcur[jb][1] = *(const f16x8*)(kb + 32);
    }
  };
  const int jbase = jh * 512;
  loadK(jbase);

  f16x8 vreg[4];  // first 32-j half of V tile, prefetched

  for (int t = 0; t < 8; t++) {
    int j0 = jbase + t * 64;
    // ---- S = (QK^T)^T for head h=wave -> S plane [h][i][j]
    f32x4 sres[4];
    #pragma unroll
    for (int jb = 0; jb < 4; jb++) {
      f32x4 s = __builtin_amdgcn_mfma_f32_16x16x32_f16(kcur[jb][0], qf[0], zero, 0, 0, 0);
      sres[jb] = __builtin_amdgcn_mfma_f32_16x16x32_f16(kcur[jb][1], qf[1], s, 0, 0, 0);
    }
    #pragma unroll
    for (int jb = 0; jb < 4; jb++) {
      f16x4 sv;
      #pragma unroll
      for (int r = 0; r < 4; r++) sv[r] = (_Float16)sres[jb][r];
      *(f16x4*)(Sp + lds_off(wave, l16, jb * 16 + quad * 4)) = sv;
    }
    // prefetch next K tile + this tile's first V half (resident after drain)
    if (t < 7) loadK(j0 + 64);
    #pragma unroll
    for (int nt = 0; nt < 4; nt++)
      vreg[nt] = *(const f16x8*)(vbase + (size_t)(nt * 16) * N_ + j0);
    __syncthreads();
    // ---- mix1 (row i=wave) -> exp (unnormalized) -> P planes + l accumulate
    #pragma unroll
    for (int cg = 0; cg < 4; cg++) {
      f16x4 sf;
      #pragma unroll
      for (int t4 = 0; t4 < 4; t4++)
        sf[t4] = Sp[lds_off(quad * 4 + t4, wave, cg * 16 + l16)];
      f32x4 a = __builtin_amdgcn_mfma_f32_16x16x16f16(sf, w1a, b1i, 0, 0, 0);
      f16x4 pv;
      #pragma unroll
      for (int r = 0; r < 4; r++) {
        float e = __expf(a[r]);
        lacc += e;
        pv[r] = (_Float16)e;
      }
      *(f16x4*)(Pp + lds_off(l16, wave, cg * 16 + quad * 4)) = pv;
    }
    __syncthreads();
    // ---- PV: U_e += V @ P_e^T (e=wave): C[m=d][n=i]
    f16x8 pf0 = *(const f16x8*)(Pp + lds_off(wave, l16, quad * 8));
    f16x8 pf1 = *(const f16x8*)(Pp + lds_off(wave, l16, 32 + quad * 8));
    #pragma unroll
    for (int nt = 0; nt < 4; nt++)
      uacc[nt] = __builtin_amdgcn_mfma_f32_16x16x32_f16(vreg[nt], pf0, uacc[nt], 0, 0, 0);
    #pragma unroll
    for (int nt = 0; nt < 4; nt++) {
      f16x8 vf = *(const f16x8*)(vbase + (size_t)(nt * 16) * N_ + j0 + 32);
      uacc[nt] = __builtin_amdgcn_mfma_f32_16x16x32_f16(vf, pf1, uacc[nt], 0, 0, 0);
    }
  }

  // ---------------- emit partials ----------------
  // lacc holds partial l for (e=l16, i=wave); reduce over quad (rows j)
  lacc += __shfl_xor(lacc, 16);
  lacc += __shfl_xor(lacc, 32);
  const size_t bi = ((size_t)(b * 64 + it)) * 2 + jh;
  if (quad == 0) lpart[bi * 256 + l16 * 16 + wave] = lacc;
  // U partial layout [e][i][d] f16 (e=wave, i=l16, d=nt*16+quad*4+r)
  #pragma unroll
  for (int nt = 0; nt < 4; nt++) {
    f16x4 u;
    #pragma unroll
    for (int r = 0; r < 4; r++) u[r] = (_Float16)uacc[nt][r];
    *(f16x4*)(upart + bi * 16384 + wave * 1024 + l16 * 64 + nt * 16 + quad * 4) = u;
  }
}

// ---------------- attention reduce: sum partials, normalize, mix2, store ----------------
// grid (64 i-tiles, 4 b), 1024 thr = 16 waves.
__global__ __launch_bounds__(1024, 2) void attn_red(
    const _Float16* __restrict__ upart, const float* __restrict__ lpart,
    const _Float16* __restrict__ w2f, const float* __restrict__ bsum,
    _Float16* __restrict__ ob) {
  __shared__ __align__(16) _Float16 Uf[18560];  // plane stride 1160, row 72
  const int tid = threadIdx.x;
  const int it = blockIdx.x;
  const int b = blockIdx.y;
  const size_t bi0 = ((size_t)(b * 64 + it)) * 2;

  // each thread owns 16 contiguous f16 of a 16x16x64 partial
  int e = tid >> 6, ii = (tid >> 2) & 15, d0 = (tid & 3) * 16;
  float l = lpart[bi0 * 256 + e * 16 + ii] + lpart[(bi0 + 1) * 256 + e * 16 + ii];
  float invl = 1.0f / l;
  const _Float16* u0 = upart + bi0 * 16384 + tid * 16;
  const _Float16* u1 = u0 + 16384;
  f16x8 x0 = *(const f16x8*)u0, x1 = *(const f16x8*)(u0 + 8);
  f16x8 y0 = *(const f16x8*)u1, y1 = *(const f16x8*)(u1 + 8);
  f16x8 o0, o1;
  #pragma unroll
  for (int k = 0; k < 8; k++) {
    o0[k] = (_Float16)(((float)x0[k] + (float)y0[k]) * invl);
    o1[k] = (_Float16)(((float)x1[k] + (float)y1[k]) * invl);
  }
  _Float16* dst = Uf + e * 1160 + ii * 72 + d0;
  *(f16x8*)dst = o0;
  *(f16x8*)(dst + 8) = o1;
  __syncthreads();

  // mix2: O[g][(i,d)] = sum_e W2[g,e] Un[e][(i,d)]; wave = i
  const int wave = tid >> 6, lane = tid & 63;
  const int quad = lane >> 4, l16 = lane & 15;
  const f32x4 zero = {0.f, 0.f, 0.f, 0.f};
  const size_t bN = (size_t)b * N_;
  f16x4 w2a = *(const f16x4*)(w2f + l16 * 16 + quad * 4);
  #pragma unroll
  for (int cg = 0; cg < 4; cg++) {
    f16x4 af;
    #pragma unroll
    for (int t4 = 0; t4 < 4; t4++)
      af[t4] = Uf[(quad * 4 + t4) * 1160 + wave * 72 + cg * 16 + l16];
    f32x4 o = __builtin_amdgcn_mfma_f32_16x16x16f16(af, w2a, zero, 0, 0, 0);
    // D: col=l16 -> g, row=quad*4+r -> d = cg*16+quad*4+r (i = wave)
    f32x4 bs = *(const f32x4*)(bsum + b * D_ + l16 * 64 + cg * 16 + quad * 4);
    f16x4 ov;
    #pragma unroll
    for (int r = 0; r < 4; r++) ov[r] = (_Float16)(o[r] + bs[r]);
    *(f16x4*)(ob + (bN + it * 16 + wave) * D_ + l16 * 64 + cg * 16 + quad * 4) = ov;
  }
}

// ---------------------------------------------------------------------------
extern "C" void kernel_launch(void* const* d_in, const int* in_sizes, int n_in,
                              void* d_out, int out_size, void* d_ws, size_t ws_size,
                              hipStream_t stream) {
  const float* x      = (const float*)d_in[0];
  const float* ln1_w  = (const float*)d_in[1];
  const float* ln1_b  = (const float*)d_in[2];
  const float* qkv_w  = (const float*)d_in[3];
  const float* qkv_b  = (const float*)d_in[4];
  const float* plw    = (const float*)d_in[5];
  const float* plb    = (const float*)d_in[6];
  const float* pww    = (const float*)d_in[7];
  const float* pwb    = (const float*)d_in[8];
  const float* out_w  = (const float*)d_in[9];
  const float* out_b  = (const float*)d_in[10];
  const float* gamma1 = (const float*)d_in[11];
  const float* ln2_w  = (const float*)d_in[12];
  const float* ln2_b  = (const float*)d_in[13];
  const float* fc1_w  = (const float*)d_in[14];
  const float* fc1_b  = (const float*)d_in[15];
  const float* fc2_w  = (const float*)d_in[16];
  const float* fc2_b  = (const float*)d_in[17];
  const float* gamma2 = (const float*)d_in[18];
  float* out = (float*)d_out;

  char* ws = (char*)d_ws;
  _Float16* wq   = (_Float16*)(ws + 0);          // 6291456 B (lpart lives here during attn)
  _Float16* wo   = (_Float16*)(ws + 6291456);    // 2097152 B
  _Float16* wf1  = (_Float16*)(ws + 8388608);    // 8388608 B (hosts mix tables during attn)
  _Float16* wf2  = (_Float16*)(ws + 16777216);   // 8388608 B
  float*    x1   = (float*)   (ws + 25165824);   // 16777216 B (upart lives here during attn)
  _Float16* ob   = (_Float16*)(ws + 41943040);   // 8388608 B
  _Float16* hb   = (_Float16*)(ws + 50331648);   // 8388608 B
  _Float16* qkvb = (_Float16*)(ws + 58720256);   // 25165824 B
  _Float16* vtb  = (_Float16*)(ws + 83886080);   // 8388608 B
  _Float16* fb   = (_Float16*)(ws + 58720256);   // 33554432 B, aliases qkvb+vtb (dead by then)
  _Float16* w1f  = (_Float16*)(ws + 8388608);          // 512 B
  _Float16* w2f  = (_Float16*)(ws + 8388608 + 512);    // 512 B
  float*    bsum = (float*)   (ws + 8388608 + 1024);   // 16384 B
  // attention partials (regions dead during attention):
  float*    lpart = (float*)   (ws + 0);         // 512 * 256 * 4 B = 524288
  _Float16* upart = (_Float16*)(ws + 25165824);  // 512 * 16384 * 2 B = 16777216
  if (ws_size < 92274688) return;

  cast_f32_f16<<<3072 * 1024 / 1024, 256, 0, stream>>>(qkv_w, wq, 3072 * 1024);
  cast_f32_f16<<<1024 * 1024 / 1024, 256, 0, stream>>>(out_w, wo, 1024 * 1024);
  prep_w<<<1, 256, 0, stream>>>(plw, pww, w1f, w2f, bsum);

  ln_f16<<<4096, 256, 0, stream>>>(x, ln1_w, ln1_b, hb);
  gemm_nt<0><<<dim3(24, 32), 256, 0, stream>>>(hb, wq, qkv_b, M_, 3 * D_, D_, qkvb, nullptr, nullptr, nullptr);
  transpose_vsum<<<dim3(16, 16, 4), 256, 0, stream>>>(qkvb, pwb, vtb, bsum);
  attn_th<<<dim3(64, 2, 4), 1024, 0, stream>>>(qkvb, vtb, w1f, plb, upart, lpart);
  attn_red<<<dim3(64, 4), 1024, 0, stream>>>(upart, lpart, w2f, bsum, ob);
  gemm_nt<1><<<dim3(8, 32), 256, 0, stream>>>(ob, wo, out_b, M_, D_, D_, nullptr, x1, x, gamma1);

  cast_f32_f16<<<4096 * 1024 / 1024, 256, 0, stream>>>(fc1_w, wf1, 4096 * 1024);
  cast_f32_f16<<<4096 * 1024 / 1024, 256, 0, stream>>>(fc2_w, wf2, 4096 * 1024);

  ln_f16<<<4096, 256, 0, stream>>>(x1, ln2_w, ln2_b, hb);
  gemm_nt<2><<<dim3(32, 32), 256, 0, stream>>>(hb, wf1, fc1_b, M_, FF_, D_, fb, nullptr, nullptr, nullptr);
  gemm_nt<1><<<dim3(8, 32), 256, 0, stream>>>(fb, wf2, fc2_b, M_, D_, FF_, nullptr, out, x1, gamma2);
}